// Round 4
// baseline (82.401 us; speedup 1.0000x reference)
//
#include <hip/hip_runtime.h>

// KAN neuron, Chebyshev basis, degree 8 (fixed).
// y[b] = sum_d sum_k c[d*9+k] * T_k(x[b,d]);  x:(16384,512) f32, c:(4608,) f32.
//
// Roofline: 33.6 MB x read -> ~6 us at 5.5-6.3 TB/s. R2 evidence: bench
// dur_us (~75) includes ~55 us of harness stream work (268 MB d_ws poison
// fills @44 us dominate the rocprof top-5; kernel never appears -> <43 us).
// R3/R4: attack latency-boundedness — 2-deep software pipeline (prefetch next
// row before computing current), nontemporal x loads, launch_bounds(256,4).
// R3 failed compile: __builtin_nontemporal_load needs a native vector type,
// not HIP_vector_type<float,4> — use ext_vector_type(4) alias.

#define DIM 512
#define DEGP1 9
#define NCOEFF (DIM * DEGP1)      // 4608
#define NCOEFF4 (NCOEFF / 4)      // 1152

typedef float fx4 __attribute__((ext_vector_type(4)));

__global__ __launch_bounds__(256, 4)
void kan_cheb_kernel(const float* __restrict__ x,
                     const float* __restrict__ coeff,
                     float* __restrict__ out,
                     int batch) {
    // Coeffs transposed in LDS to [k][d]: per-wave hoist is 18 conflict-free
    // ds_read_b128 (byte addr 2048*k + 16*lane).
    __shared__ float cs[DEGP1 * DIM];  // 18 KB

    const int tid = threadIdx.x;

    // ---- Block-cooperative coalesced fill + transpose (once per block) ----
    const fx4* coeff4 = (const fx4*)coeff;
    for (int idx = tid; idx < NCOEFF4; idx += 256) {
        const fx4 v = coeff4[idx];
        const int g = 4 * idx;
#pragma unroll
        for (int m = 0; m < 4; ++m) {
            const int gg = g + m;
            const int d = gg / DEGP1;
            const int k = gg - d * DEGP1;
            cs[k * DIM + d] = v[m];
        }
    }
    __syncthreads();

    const int lane = tid & 63;
    const int wave_in_block = tid >> 6;
    const int waves_per_block = blockDim.x >> 6;
    const int gwave = blockIdx.x * waves_per_block + wave_in_block;
    const int nwaves = gridDim.x * waves_per_block;

    const int d0 = 4 * lane;        // first float4 group of dims
    const int d1 = 256 + 4 * lane;  // second float4 group of dims

    // ---- Per-wave register hoist of this lane's 8x9 coefficients ----
    float c[8][DEGP1];
#pragma unroll
    for (int k = 0; k < DEGP1; ++k) {
        const fx4 va = *(const fx4*)&cs[k * DIM + d0];
        const fx4 vb = *(const fx4*)&cs[k * DIM + d1];
        c[0][k] = va.x; c[1][k] = va.y; c[2][k] = va.z; c[3][k] = va.w;
        c[4][k] = vb.x; c[5][k] = vb.y; c[6][k] = vb.z; c[7][k] = vb.w;
    }

    // ---- Streaming row loop, 2-deep software pipeline ----
    int row = gwave;
    fx4 xa, xb;
    if (row < batch) {
        const size_t base = (size_t)row * DIM;
        xa = __builtin_nontemporal_load((const fx4*)(x + base + d0));
        xb = __builtin_nontemporal_load((const fx4*)(x + base + d1));
    }

    while (row < batch) {
        const int next = row + nwaves;
        fx4 na = {0.f, 0.f, 0.f, 0.f}, nb = {0.f, 0.f, 0.f, 0.f};
        if (next < batch) {
            const size_t nbase = (size_t)next * DIM;
            na = __builtin_nontemporal_load((const fx4*)(x + nbase + d0));
            nb = __builtin_nontemporal_load((const fx4*)(x + nbase + d1));
        }

        const float xs[8] = {xa.x, xa.y, xa.z, xa.w, xb.x, xb.y, xb.z, xb.w};
        float acc = 0.0f;
#pragma unroll
        for (int j = 0; j < 8; ++j) {
            const float xv = xs[j];
            float t0 = 1.0f;
            float t1 = xv;
            float a  = fmaf(c[j][1], xv, c[j][0]);
            const float x2 = xv + xv;
#pragma unroll
            for (int k = 2; k < DEGP1; ++k) {
                const float t2 = fmaf(x2, t1, -t0);  // T_k = 2x*T_{k-1} - T_{k-2}
                a  = fmaf(c[j][k], t2, a);
                t0 = t1;
                t1 = t2;
            }
            acc += a;
        }

        // Wave-level sum across 64 lanes.
#pragma unroll
        for (int off = 32; off > 0; off >>= 1)
            acc += __shfl_down(acc, off, 64);

        if (lane == 0) out[row] = acc;

        xa = na; xb = nb;
        row = next;
    }
}

extern "C" void kernel_launch(void* const* d_in, const int* in_sizes, int n_in,
                              void* d_out, int out_size, void* d_ws, size_t ws_size,
                              hipStream_t stream) {
    const float* x     = (const float*)d_in[0];
    const float* coeff = (const float*)d_in[1];
    // d_in[2] is degree == 8, fixed; hard-coded in the kernel.
    float* out = (float*)d_out;

    const int batch = in_sizes[0] / DIM;  // 16384

    // 1024 blocks x 256 threads = 4096 waves -> 4 rows per wave.
    dim3 grid(1024), block(256);
    hipLaunchKernelGGL(kan_cheb_kernel, grid, block, 0, stream,
                       x, coeff, out, batch);
}

// Round 5
// 75.734 us; speedup vs baseline: 1.0880x; 1.0880x over previous
//
#include <hip/hip_runtime.h>

// KAN neuron, Chebyshev basis, degree 8 (fixed).
// y[b] = sum_d sum_k c[d*9+k] * T_k(x[b,d]);  x:(16384,512) f32, c:(4608,) f32.
//
// Evidence so far: measured dur_us includes ~57 us of per-iteration harness
// work (268 MB d_ws poison @44 us + x restore); kernel portion ~18-25 us vs
// ~6-8 us floor. R4's nontemporal loads regressed (x is L2/L3-warm from the
// harness restore copy — nt bypasses it). R5: plain cached loads; batch ==
// 4*nwaves exactly, so fully unroll: issue all 8 float4 loads per wave up
// front (max MLP), compute 4 rows, interleave the 4 shuffle reductions.

#define DIM 512
#define DEGP1 9
#define NCOEFF (DIM * DEGP1)      // 4608
#define NCOEFF4 (NCOEFF / 4)      // 1152

typedef float fx4 __attribute__((ext_vector_type(4)));

__device__ __forceinline__ float cheb_dot(const fx4 a, const fx4 b,
                                          const float c[8][DEGP1]) {
    const float xs[8] = {a.x, a.y, a.z, a.w, b.x, b.y, b.z, b.w};
    float acc = 0.0f;
#pragma unroll
    for (int j = 0; j < 8; ++j) {
        const float xv = xs[j];
        float t0 = 1.0f;
        float t1 = xv;
        float r  = fmaf(c[j][1], xv, c[j][0]);
        const float x2 = xv + xv;
#pragma unroll
        for (int k = 2; k < DEGP1; ++k) {
            const float t2 = fmaf(x2, t1, -t0);  // T_k = 2x*T_{k-1} - T_{k-2}
            r  = fmaf(c[j][k], t2, r);
            t0 = t1;
            t1 = t2;
        }
        acc += r;
    }
    return acc;
}

__global__ __launch_bounds__(256, 4)
void kan_cheb_kernel(const float* __restrict__ x,
                     const float* __restrict__ coeff,
                     float* __restrict__ out,
                     int batch) {
    // Coeffs transposed in LDS to [k][d]: per-wave hoist is 18 conflict-free
    // ds_read_b128 (byte addr 2048*k + 16*lane).
    __shared__ float cs[DEGP1 * DIM];  // 18 KB

    const int tid = threadIdx.x;

    // ---- Block-cooperative coalesced fill + transpose (once per block) ----
    const fx4* coeff4 = (const fx4*)coeff;
    for (int idx = tid; idx < NCOEFF4; idx += 256) {
        const fx4 v = coeff4[idx];
        const int g = 4 * idx;
#pragma unroll
        for (int m = 0; m < 4; ++m) {
            const int gg = g + m;
            const int d = gg / DEGP1;
            const int k = gg - d * DEGP1;
            cs[k * DIM + d] = v[m];
        }
    }
    __syncthreads();

    const int lane = tid & 63;
    const int wave_in_block = tid >> 6;
    const int waves_per_block = blockDim.x >> 6;
    const int gwave = blockIdx.x * waves_per_block + wave_in_block;
    const int nwaves = gridDim.x * waves_per_block;

    const int d0 = 4 * lane;        // first float4 group of dims
    const int d1 = 256 + 4 * lane;  // second float4 group of dims

    // ---- Per-wave register hoist of this lane's 8x9 coefficients ----
    float c[8][DEGP1];
#pragma unroll
    for (int k = 0; k < DEGP1; ++k) {
        const fx4 va = *(const fx4*)&cs[k * DIM + d0];
        const fx4 vb = *(const fx4*)&cs[k * DIM + d1];
        c[0][k] = va.x; c[1][k] = va.y; c[2][k] = va.z; c[3][k] = va.w;
        c[4][k] = vb.x; c[5][k] = vb.y; c[6][k] = vb.z; c[7][k] = vb.w;
    }

    if (batch == 4 * nwaves) {
        // ---- Fast path: exactly 4 rows per wave; all 8 loads in flight ----
        const int r = gwave;
        const size_t stride = (size_t)nwaves * DIM;
        const size_t s0 = (size_t)r * DIM;

        fx4 A[4], B[4];
#pragma unroll
        for (int j = 0; j < 4; ++j) {
            A[j] = *(const fx4*)(x + s0 + (size_t)j * stride + d0);
            B[j] = *(const fx4*)(x + s0 + (size_t)j * stride + d1);
        }

        float acc[4];
#pragma unroll
        for (int j = 0; j < 4; ++j)
            acc[j] = cheb_dot(A[j], B[j], c);

        // Interleaved wave reductions (4 independent shfl chains).
#pragma unroll
        for (int off = 32; off > 0; off >>= 1) {
#pragma unroll
            for (int j = 0; j < 4; ++j)
                acc[j] += __shfl_down(acc[j], off, 64);
        }

        if (lane == 0) {
#pragma unroll
            for (int j = 0; j < 4; ++j)
                out[r + j * nwaves] = acc[j];
        }
    } else {
        // ---- Generic fallback (any batch) ----
        for (int row = gwave; row < batch; row += nwaves) {
            const size_t base = (size_t)row * DIM;
            const fx4 xa = *(const fx4*)(x + base + d0);
            const fx4 xb = *(const fx4*)(x + base + d1);
            float acc = cheb_dot(xa, xb, c);
#pragma unroll
            for (int off = 32; off > 0; off >>= 1)
                acc += __shfl_down(acc, off, 64);
            if (lane == 0) out[row] = acc;
        }
    }
}

extern "C" void kernel_launch(void* const* d_in, const int* in_sizes, int n_in,
                              void* d_out, int out_size, void* d_ws, size_t ws_size,
                              hipStream_t stream) {
    const float* x     = (const float*)d_in[0];
    const float* coeff = (const float*)d_in[1];
    // d_in[2] is degree == 8, fixed; hard-coded in the kernel.
    float* out = (float*)d_out;

    const int batch = in_sizes[0] / DIM;  // 16384

    // 1024 blocks x 256 threads = 4096 waves -> exactly 4 rows per wave.
    dim3 grid(1024), block(256);
    hipLaunchKernelGGL(kan_cheb_kernel, grid, block, 0, stream,
                       x, coeff, out, batch);
}